// Round 5
// baseline (444.769 us; speedup 1.0000x reference)
//
#include <hip/hip_runtime.h>
#include <hip/hip_bf16.h>

// Problem constants (B=64, T=4096, D=256)
constexpr int DD  = 256;
constexpr int TT  = 4096;
constexpr int NBB = 64;
constexpr int TCC = 32;                    // rows per chunk
constexpr int SPLIT = 8;                   // blocks per batch over T
constexpr int NCHUNK = (TT / SPLIT) / TCC; // 16 chunks per block
constexpr int ROWB = DD * 2;               // 512 B per bf16 row in LDS

typedef __bf16 bf16_t;
typedef __bf16 bf16x8 __attribute__((ext_vector_type(8)));
typedef float  f32x4  __attribute__((ext_vector_type(4)));

__device__ __forceinline__ float fast_tanh(float x) {
  // tanh(x) = 1 - 2/(exp(2x)+1); exact at +-inf, ~1e-6 rel error
  float e = __expf(x + x);
  return 1.0f - __fdividef(2.0f, e + 1.0f);
}

// ---- prep: WkT_bf16[n][d] = bf16(Wk[d][n]) --------------------------------
__global__ __launch_bounds__(256) void prep_wkT_kernel(
    const float* __restrict__ Wk, unsigned short* __restrict__ wkT) {
  int d = blockIdx.x;
  int n = threadIdx.x;
  union { bf16_t h; unsigned short u; } cv;
  cv.h = (bf16_t)Wk[d * DD + n];
  wkT[n * DD + d] = cv.u;
}

// ---- prep: qb2[b][d] = x[b,T-1,:]@Wq + bq + bk ----------------------------
__global__ __launch_bounds__(256) void prep_q_kernel(
    const float* __restrict__ x, const float* __restrict__ Wq,
    const float* __restrict__ bq, const float* __restrict__ bk,
    float* __restrict__ qb2) {
  __shared__ float xl[DD];
  int b = blockIdx.x, tid = threadIdx.x;
  xl[tid] = x[((size_t)b * TT + (TT - 1)) * DD + tid];
  __syncthreads();
  float a = bq[tid] + bk[tid];
  for (int k = 0; k < DD; ++k) a = fmaf(xl[k], Wq[k * DD + tid], a);
  qb2[b * DD + tid] = a;
}

// ---- main: reg-staged bf16 pipeline, 8 waves x 32 cols, 16 waves/CU -------
// Per chunk j: issue global loads(j+1) -> regs; MFMA k-GEMM from bf16 LDS;
// tanh-score + shfl reduce; exp weights; bf16 weighted x-accum from LDS;
// cvt+ds_write regs -> LDS[(j+1)&1]; one trailing barrier.
__global__ __launch_bounds__(512, 4) void fused_scores_kernel(
    const float* __restrict__ x, const unsigned short* __restrict__ wkT,
    const float* __restrict__ qb2, const float* __restrict__ wout,
    float* __restrict__ partials) {
  __shared__ __align__(16) unsigned short xs[2][TCC * DD]; // 2 x 16 KB bf16
  __shared__ float epart[8 * TCC];                          // 1 KB (reused)
  __shared__ float wbuf[TCC + 8];

  const int tid = threadIdx.x;
  const int b   = blockIdx.y;
  const int bx  = blockIdx.x;
  const int wid = tid >> 6;   // 0..7
  const int l   = tid & 63;
  const int l15 = l & 15;
  const int lg  = l >> 4;

  // B fragments: wave wid owns cols [wid*32, wid*32+32): 2 nt x 8 ks = 64 VGPR
  bf16x8 bfr[2][8];
#pragma unroll
  for (int nt = 0; nt < 2; ++nt) {
    const unsigned short* wp =
        wkT + (size_t)(wid * 32 + nt * 16 + l15) * DD + lg * 8;
#pragma unroll
    for (int ks = 0; ks < 8; ++ks)
      bfr[nt][ks] = *reinterpret_cast<const bf16x8*>(wp + ks * 32);
  }

  float qcol[2], wcol[2];
#pragma unroll
  for (int nt = 0; nt < 2; ++nt) {
    int col = wid * 32 + nt * 16 + l15;
    qcol[nt] = qb2[b * DD + col];
    wcol[nt] = wout[col];
  }

  const float* xc0 = x + ((size_t)b * TT + (size_t)bx * (TT / SPLIT)) * DD;

  // staging geometry: load i covers rows i*8+wid (row&7 == wid), col4 = l
  float4 r0, r1, r2, r3;
  auto issue_loads = [&](int chunk) {
    const float4* p = reinterpret_cast<const float4*>(xc0 + (size_t)chunk * TCC * DD);
    r0 = p[0 * 512 + tid];
    r1 = p[1 * 512 + tid];
    r2 = p[2 * 512 + tid];
    r3 = p[3 * 512 + tid];
  };
  auto write_lds = [&](int bufi) {
    char* base = (char*)xs[bufi];
    const float4 rr[4] = {r0, r1, r2, r3};
#pragma unroll
    for (int i = 0; i < 4; ++i) {
      int row = i * 8 + wid;                     // row & 7 == wid
      union { bf16_t h[4]; uint2 u; } pk;
      pk.h[0] = (bf16_t)rr[i].x; pk.h[1] = (bf16_t)rr[i].y;
      pk.h[2] = (bf16_t)rr[i].z; pk.h[3] = (bf16_t)rr[i].w;
      *reinterpret_cast<uint2*>(base + row * ROWB + ((l * 8) ^ (wid << 4))) = pk.u;
    }
  };

  float s_run = 0.0f, cacc = 0.0f;
  const int rh = tid >> 8;      // 0: rows 0-15, 1: rows 16-31
  const int d  = tid & 255;
  const int sw = (l15 & 7) << 4;

  issue_loads(0);
  write_lds(0);
  __syncthreads();

  for (int j = 0; j < NCHUNK; ++j) {
    const char* xb = (const char*)xs[j & 1];
    if (j + 1 < NCHUNK) issue_loads(j + 1);

    // ---- k-GEMM: [32 x 256] x [256 x 32 cols for this wave] --------------
    f32x4 acc[2][2];
#pragma unroll
    for (int mt = 0; mt < 2; ++mt)
#pragma unroll
      for (int nt = 0; nt < 2; ++nt)
        acc[mt][nt] = f32x4{0.f, 0.f, 0.f, 0.f};

#pragma unroll
    for (int ks = 0; ks < 8; ++ks) {
#pragma unroll
      for (int mt = 0; mt < 2; ++mt) {
        int row = mt * 16 + l15;
        bf16x8 afr = *reinterpret_cast<const bf16x8*>(
            xb + row * ROWB + ((ks * 64 + lg * 16) ^ sw));
#pragma unroll
        for (int nt = 0; nt < 2; ++nt)
          acc[mt][nt] = __builtin_amdgcn_mfma_f32_16x16x32_bf16(
              afr, bfr[nt][ks], acc[mt][nt], 0, 0, 0);
      }
    }

    // ---- scores: e_t += sum_col tanh(qb2+k)*wout over this wave's 32 cols -
    float rs[2][4];
#pragma unroll
    for (int mt = 0; mt < 2; ++mt)
#pragma unroll
      for (int r = 0; r < 4; ++r) rs[mt][r] = 0.0f;
#pragma unroll
    for (int nt = 0; nt < 2; ++nt) {
      float q = qcol[nt], w = wcol[nt];
#pragma unroll
      for (int mt = 0; mt < 2; ++mt)
#pragma unroll
        for (int r = 0; r < 4; ++r)
          rs[mt][r] += fast_tanh(q + acc[mt][nt][r]) * w;
    }
#pragma unroll
    for (int s = 1; s < 16; s <<= 1) {
#pragma unroll
      for (int mt = 0; mt < 2; ++mt)
#pragma unroll
        for (int r = 0; r < 4; ++r)
          rs[mt][r] += __shfl_xor(rs[mt][r], s, 64);
    }
    if (l15 == 0) {
#pragma unroll
      for (int mt = 0; mt < 2; ++mt)
#pragma unroll
        for (int r = 0; r < 4; ++r)
          epart[wid * TCC + mt * 16 + lg * 4 + r] = rs[mt][r];
    }
    __syncthreads();

    if (tid < TCC) {
      float e = 0.0f;
#pragma unroll
      for (int w = 0; w < 8; ++w) e += epart[w * TCC + tid];
      wbuf[tid] = __expf(e);
    }
    __syncthreads();

    // ---- weighted accumulation of bf16 x from LDS ------------------------
#pragma unroll
    for (int t = 0; t < 16; ++t) {
      int row = rh * 16 + t;
      float wt = wbuf[row];
      unsigned short uh = *reinterpret_cast<const unsigned short*>(
          xb + row * ROWB + ((d * 2) ^ ((row & 7) << 4)));
      float xv = __uint_as_float(((unsigned)uh) << 16);
      s_run += wt;
      cacc = fmaf(wt, xv, cacc);
    }

    if (j + 1 < NCHUNK) write_lds((j + 1) & 1);
    __syncthreads();
  }

  // ---- merge the two row-halves, emit partial (S, c[256]) ----------------
  float* csum = epart;  // reuse
  if (rh == 1) {
    csum[d] = cacc;
    if (tid == 256) wbuf[TCC] = s_run;
  }
  __syncthreads();
  if (rh == 0) {
    float ct = cacc + csum[d];
    float* p = partials + ((size_t)b * SPLIT + bx) * 257;
    if (tid == 0) p[0] = s_run + wbuf[TCC];
    p[1 + d] = ct;
  }
}

// ---- combine partials, out = (C/S)@Wv + bv --------------------------------
__global__ __launch_bounds__(256) void combine_kernel(
    const float* __restrict__ partials, const float* __restrict__ Wv,
    const float* __restrict__ bv, float* __restrict__ out) {
  __shared__ float att[DD];
  int b = blockIdx.x, tid = threadIdx.x;
  const float* pb = partials + (size_t)b * SPLIT * 257;
  float S = 0.0f, C = 0.0f;
  for (int j = 0; j < SPLIT; ++j) {
    S += pb[j * 257];
    C += pb[j * 257 + 1 + tid];
  }
  att[tid] = C;
  __syncthreads();
  float inv = __fdividef(1.0f, S);
  float sum = 0.0f;
  for (int k = 0; k < DD; ++k) sum = fmaf(att[k], Wv[k * DD + tid], sum);
  out[b * DD + tid] = fmaf(sum, inv, bv[tid]);
}

extern "C" void kernel_launch(void* const* d_in, const int* in_sizes, int n_in,
                              void* d_out, int out_size, void* d_ws, size_t ws_size,
                              hipStream_t stream) {
  const float* x    = (const float*)d_in[0];
  const float* Wq   = (const float*)d_in[1];
  const float* bq   = (const float*)d_in[2];
  const float* Wk   = (const float*)d_in[3];
  const float* bk   = (const float*)d_in[4];
  const float* Wv   = (const float*)d_in[5];
  const float* bv   = (const float*)d_in[6];
  const float* Wout = (const float*)d_in[7];
  float* out = (float*)d_out;

  char* ws = (char*)d_ws;
  unsigned short* wkT = (unsigned short*)ws;       // 128 KB
  float* qb2      = (float*)(ws + 131072);         // 64 KB
  float* partials = (float*)(ws + 131072 + 65536); // 64*8*257*4 = 514 KB

  prep_wkT_kernel<<<dim3(256), dim3(256), 0, stream>>>(Wk, wkT);
  prep_q_kernel<<<dim3(64), dim3(256), 0, stream>>>(x, Wq, bq, bk, qb2);
  fused_scores_kernel<<<dim3(SPLIT, NBB), dim3(512), 0, stream>>>(
      x, wkT, qb2, Wout, partials);
  combine_kernel<<<dim3(64), dim3(256), 0, stream>>>(partials, Wv, bv, out);
}